// Round 13
// baseline (30.459 us; speedup 1.0000x reference)
//
#include <hip/hip_runtime.h>

typedef short bf16x8 __attribute__((ext_vector_type(8)));
typedef float f32x4  __attribute__((ext_vector_type(4)));
typedef unsigned int u32;

#define HH 128
#define WW 128

__device__ __forceinline__ u32 cvt_pk_bf16(float lo, float hi) {
    u32 r;
    asm volatile("v_cvt_pk_bf16_f32 %0, %1, %2" : "=v"(r) : "v"(lo), "v"(hi));
    return r;   // low16 = bf16(lo), high16 = bf16(hi)
}

// LDS-only barrier (does not drain global loads/stores).
__device__ __forceinline__ void lds_barrier() {
    asm volatile("s_waitcnt lgkmcnt(0)" ::: "memory");
    __builtin_amdgcn_s_barrier();
    __builtin_amdgcn_sched_barrier(0);
}
// Full barrier: drain vmcnt (global_load_lds completions) + lgkm, then join.
__device__ __forceinline__ void full_barrier() {
    asm volatile("s_waitcnt vmcnt(0) lgkmcnt(0)" ::: "memory");
    __builtin_amdgcn_s_barrier();
    __builtin_amdgcn_sched_barrier(0);
}

#define GLOBAL_LOAD_LDS16(g, l)                                              \
    __builtin_amdgcn_global_load_lds(                                        \
        (const __attribute__((address_space(1))) void*)(g),                  \
        (__attribute__((address_space(3))) void*)(l), 16, 0, 0)

// ---------------------------------------------------------------------------
// Kernel 1 (pack): x fp32 [b][ch][h][w] -> xb16 bf16 channel-last-8 in d_ws,
// laid out EXACTLY like the conv kernel's LDS row slots:
//   xb16[b][h][entry e=0..511] where e = (c>>4)*64 + ig*16 + (c&15),
//   each entry = 8 ch bf16 (16 B).  8 KB per (b,row).  Pure streaming.
// Grid: 2048 blocks (16 b x 128 rows) x 256 thr.
// ---------------------------------------------------------------------------
__global__ __launch_bounds__(256) void geps_pack_kernel(
    const float* __restrict__ x, u32* __restrict__ xb16)
{
    const int tid = threadIdx.x;
    const int b   = blockIdx.x >> 7;
    const int row = blockIdx.x & 127;
    const int cp  = tid & 63;          // col pair 0..63
    const int ig  = tid >> 6;          // channel group 0..3
    const int c0  = cp * 2;

    const float* src = x + ((size_t)(b * 32 + ig * 8) * HH + row) * WW + c0;
    float2 f[8];
    #pragma unroll
    for (int jj = 0; jj < 8; ++jj)
        f[jj] = *(const float2*)(src + (size_t)jj * HH * WW);
    u32 p0[4], p1[4];
    #pragma unroll
    for (int q = 0; q < 4; ++q) {
        p0[q] = cvt_pk_bf16(f[2 * q].x, f[2 * q + 1].x);
        p1[q] = cvt_pk_bf16(f[2 * q].y, f[2 * q + 1].y);
    }
    int didx = (c0 >> 4) * 64 + ig * 16 + (c0 & 15);
    u32* dst = xb16 + ((size_t)(b * 128 + row) * 512 + didx) * 4;
    *(uint4*)&dst[0] = make_uint4(p0[0], p0[1], p0[2], p0[3]);
    *(uint4*)&dst[4] = make_uint4(p1[0], p1[1], p1[2], p1[3]);
}

// ---------------------------------------------------------------------------
// Kernel 2 (conv): implicit-GEMM conv, 9 shifted 32x32 channel GEMMs on
// mfma_f32_16x16x32_bf16.  Staging = 10 global_load_lds dwordx4 per wave
// (1 KB contiguous each, LDS dest linear in lane) -- no VGPR round-trip,
// no staging VALU.  Weight synthesis overlaps the in-flight loads.
// Block: 512 thr (8 waves) owns 8 contiguous output rows; wave = 1 row,
// all 32 out-ch, all 8 col-tiles (B-frag feeds 2 MFMAs).
// Grid: 256 blocks (16 b x 16 groups), XCD-bijective swizzle, 1 block/CU.
// ---------------------------------------------------------------------------
__global__ __launch_bounds__(512, 1) void geps_conv_kernel(
    const u32* __restrict__ xb16, const float* __restrict__ codes,
    const float* __restrict__ weight, const float* __restrict__ A,
    const float* __restrict__ Bm, const float* __restrict__ bias,
    const float* __restrict__ bctx, float* __restrict__ out)
{
    __shared__ bf16x8 lds_x[5120];    // [10 slots][512 entries] = 80 KB
    __shared__ bf16x8 lds_w[1152];    // [9 kl][2 oh][4 kb][16 o] x 8i bf16
    __shared__ float  lds_ctx[576];
    __shared__ float  lds_b[32];

    const int tid  = threadIdx.x;
    const int l    = tid & 63;
    const int row  = tid >> 6;         // wave id 0..7 = output row in group

    // XCD-aware bijective swizzle: 256 blocks = 8 XCDs x 32 contiguous.
    const int orig = blockIdx.x;
    const int vb   = (orig & 7) * 32 + (orig >> 3);
    const int b    = vb >> 4;          // batch 0..15
    const int grp  = vb & 15;          // 8-row group 0..15
    const int h0   = grp * 8;

    // ---- Issue ALL staging loads first: rows h0-1..h0+8 -> slots 0..9 ----
    const char* xrow = (const char*)xb16 + (size_t)b * 128 * 8192;
    #pragma unroll
    for (int it = 0; it < 10; ++it) {
        int grow = (h0 - 1 + it) & 127;
        GLOBAL_LOAD_LDS16(xrow + (size_t)grow * 8192 + (size_t)tid * 16,
                          (char*)lds_x + it * 8192 + tid * 16);
    }

    // ---- ctx + bias (overlaps staging) ----
    const float c00 = codes[b * 4 + 0];
    const float c01 = codes[b * 4 + 1];
    const float c10 = codes[b * 4 + 2];
    const float c11 = codes[b * 4 + 3];
    for (int j = tid; j < 576; j += 512) {
        int i = j / 18, rem = j % 18, r = rem / 9, kl = rem % 9;
        float a0 = A[(i * 2 + 0) * 9 + kl];
        float a1 = A[(i * 2 + 1) * 9 + kl];
        lds_ctx[j] = (r == 0) ? (a0 * c00 + a1 * c10) : (a0 * c01 + a1 * c11);
    }
    if (tid < 32) lds_b[tid] = bias[tid] + c00 * bctx[tid] + c11 * bctx[32 + tid];
    lds_barrier();     // ctx visible (stage loads still in flight)

    // ---- Weight synthesis -> bf16 LDS (overlaps staging) ----
    for (int j = tid; j < 1152; j += 512) {
        int kl = j >> 7, rem = j & 127, o = rem >> 2, kb = rem & 3;
        float m0 = Bm[(o * 2 + 0) * 9 + kl];
        float m1 = Bm[(o * 2 + 1) * 9 + kl];
        float wf[8];
        #pragma unroll
        for (int jj = 0; jj < 8; ++jj) {
            int i = kb * 8 + jj;
            wf[jj] = weight[(o * 32 + i) * 9 + kl]
                   + lds_ctx[i * 18 + kl] * m0
                   + lds_ctx[i * 18 + 9 + kl] * m1;
        }
        u32 pk[4];
        #pragma unroll
        for (int q = 0; q < 4; ++q) pk[q] = cvt_pk_bf16(wf[2 * q], wf[2 * q + 1]);
        *(uint4*)&lds_w[kl * 128 + (o >> 4) * 64 + kb * 16 + (o & 15)] =
            make_uint4(pk[0], pk[1], pk[2], pk[3]);
    }
    full_barrier();    // staging + weights complete

    // ---- A fragments: all 9 taps x both oh halves (72 VGPRs) ----
    const int awb = (l >> 4) * 16 + (l & 15);
    bf16x8 af[9][2];
    #pragma unroll
    for (int kl = 0; kl < 9; ++kl)
        #pragma unroll
        for (int oh = 0; oh < 2; ++oh)
            af[kl][oh] = lds_w[kl * 128 + oh * 64 + awb];

    // ---- B-address bases per tap-column shift dl in {-1,0,1} ----
    const int p = l & 15, igf = l >> 4;
    int bb[3];
    #pragma unroll
    for (int dl = -1; dl <= 1; ++dl) {
        int pq = p + dl;                       // -1..16
        bb[dl + 1] = (pq & 15) + ((pq >> 4) << 6) + igf * 16;  // 16B-elem units
    }

    f32x4 acc[2][8];
    #pragma unroll
    for (int oh = 0; oh < 2; ++oh)
        #pragma unroll
        for (int nt = 0; nt < 8; ++nt) acc[oh][nt] = (f32x4){0.f, 0.f, 0.f, 0.f};

    // ---- Main loop: wave = row; slots row..row+2 (flat, no mod) ----
    #pragma unroll
    for (int lc = 0; lc < 3; ++lc) {
        #pragma unroll
        for (int k = 0; k < 3; ++k) {
            const bf16x8 a0 = af[k * 3 + lc][0];
            const bf16x8 a1 = af[k * 3 + lc][1];
            #pragma unroll
            for (int nt = 0; nt < 8; ++nt) {
                int t = (bb[lc] + nt * 64) & 511;  // col wrap (512 entries/row)
                bf16x8 bfv = lds_x[(row + k) * 512 + t];
                acc[0][nt] = __builtin_amdgcn_mfma_f32_16x16x32_bf16(
                    a0, bfv, acc[0][nt], 0, 0, 0);
                acc[1][nt] = __builtin_amdgcn_mfma_f32_16x16x32_bf16(
                    a1, bfv, acc[1][nt], 0, 0, 0);
            }
        }
    }

    // ---- Epilogue: bias + store (D: col=lane&15 -> w, row=(lane>>4)*4+reg -> o) ----
    float blr[2][4];
    #pragma unroll
    for (int oh = 0; oh < 2; ++oh)
        #pragma unroll
        for (int r = 0; r < 4; ++r)
            blr[oh][r] = lds_b[oh * 16 + (l >> 4) * 4 + r];

    const size_t obase = ((size_t)(b * 32 + (l >> 4) * 4) * HH + h0 + row) * WW + p;
    #pragma unroll
    for (int oh = 0; oh < 2; ++oh)
        #pragma unroll
        for (int nt = 0; nt < 8; ++nt)
            #pragma unroll
            for (int r = 0; r < 4; ++r)
                out[obase + (size_t)(oh * 16 + r) * (HH * WW) + nt * 16] =
                    acc[oh][nt][r] + blr[oh][r];
}

// ---------------------------------------------------------------------------
// Fallback (R12 monolithic, known-good 23.7 us) if ws_size < 16.8 MB.
// ---------------------------------------------------------------------------
__global__ __launch_bounds__(512, 1) void geps_mono_kernel(
    const float* __restrict__ x, const float* __restrict__ codes,
    const float* __restrict__ weight, const float* __restrict__ A,
    const float* __restrict__ Bm, const float* __restrict__ bias,
    const float* __restrict__ bctx, float* __restrict__ out)
{
    __shared__ bf16x8 lds_x[3072];
    __shared__ bf16x8 lds_w[1152];
    __shared__ float  lds_ctx[576];
    __shared__ float  lds_b[32];

    const int tid  = threadIdx.x;
    const int l    = tid & 63;
    const int wvid = tid >> 6;
    const int row  = wvid >> 2;
    const int nq   = wvid & 3;

    const int orig = blockIdx.x;
    const int vb   = (orig & 7) * 32 + (orig >> 3);
    const int b    = vb >> 4;
    const int grp  = vb & 15;
    const int h0   = grp * 8;

    const float c00 = codes[b * 4 + 0];
    const float c01 = codes[b * 4 + 1];
    const float c10 = codes[b * 4 + 2];
    const float c11 = codes[b * 4 + 3];

    for (int j = tid; j < 576; j += 512) {
        int i = j / 18, rem = j % 18, r = rem / 9, kl = rem % 9;
        float a0 = A[(i * 2 + 0) * 9 + kl];
        float a1 = A[(i * 2 + 1) * 9 + kl];
        lds_ctx[j] = (r == 0) ? (a0 * c00 + a1 * c10) : (a0 * c01 + a1 * c11);
    }
    if (tid < 32) lds_b[tid] = bias[tid] + c00 * bctx[tid] + c11 * bctx[32 + tid];
    lds_barrier();

    #pragma unroll
    for (int it = 0; it < 2; ++it) {
        int idx = it * 512 + tid;
        int cp  = idx & 63;
        int ig  = (idx >> 6) & 3;
        int rr  = idx >> 8;
        int c0  = cp * 2;
        int grow = (h0 - 1 + rr) & 127;
        const float* src = x + ((size_t)(b * 32 + ig * 8) * HH + grow) * WW + c0;
        float2 f[8];
        #pragma unroll
        for (int jj = 0; jj < 8; ++jj)
            f[jj] = *(const float2*)(src + (size_t)jj * HH * WW);
        u32 p0[4], p1[4];
        #pragma unroll
        for (int q = 0; q < 4; ++q) {
            p0[q] = cvt_pk_bf16(f[2 * q].x, f[2 * q + 1].x);
            p1[q] = cvt_pk_bf16(f[2 * q].y, f[2 * q + 1].y);
        }
        int didx = rr * 512 + (c0 >> 4) * 64 + ig * 16 + (c0 & 15);
        *(uint4*)&lds_x[didx]     = make_uint4(p0[0], p0[1], p0[2], p0[3]);
        *(uint4*)&lds_x[didx + 1] = make_uint4(p1[0], p1[1], p1[2], p1[3]);
    }
    for (int j = tid; j < 1152; j += 512) {
        int kl = j >> 7, rem = j & 127, o = rem >> 2, kb = rem & 3;
        float m0 = Bm[(o * 2 + 0) * 9 + kl];
        float m1 = Bm[(o * 2 + 1) * 9 + kl];
        float wf[8];
        #pragma unroll
        for (int jj = 0; jj < 8; ++jj) {
            int i = kb * 8 + jj;
            wf[jj] = weight[(o * 32 + i) * 9 + kl]
                   + lds_ctx[i * 18 + kl] * m0
                   + lds_ctx[i * 18 + 9 + kl] * m1;
        }
        u32 pk[4];
        #pragma unroll
        for (int q = 0; q < 4; ++q) pk[q] = cvt_pk_bf16(wf[2 * q], wf[2 * q + 1]);
        *(uint4*)&lds_w[kl * 128 + (o >> 4) * 64 + kb * 16 + (o & 15)] =
            make_uint4(pk[0], pk[1], pk[2], pk[3]);
    }
    lds_barrier();

    const int awb = (l >> 4) * 16 + (l & 15);
    bf16x8 af[9][2];
    #pragma unroll
    for (int kl = 0; kl < 9; ++kl)
        #pragma unroll
        for (int oh = 0; oh < 2; ++oh)
            af[kl][oh] = lds_w[kl * 128 + oh * 64 + awb];

    const int p = l & 15, igf = l >> 4;
    int bb[3];
    #pragma unroll
    for (int dl = -1; dl <= 1; ++dl) {
        int pq = p + dl;
        bb[dl + 1] = (pq & 15) + ((pq >> 4) << 6) + igf * 16;
    }
    float blr[2][4];
    #pragma unroll
    for (int oh = 0; oh < 2; ++oh)
        #pragma unroll
        for (int r = 0; r < 4; ++r)
            blr[oh][r] = lds_b[oh * 16 + (l >> 4) * 4 + r];

    const size_t obase0 = (size_t)(b * 32 + (l >> 4) * 4) * (HH * WW) + p;

    #pragma unroll
    for (int c = 0; c < 4; ++c) {
        float2 pf[8];
        int pcp = 0, pig = 0, prr = 0;
        if (c < 3) {
            int idx = tid;
            pcp = idx & 63;
            pig = (idx >> 6) & 3;
            prr = 4 + 2 * c + (idx >> 8);
            int grow = (h0 - 1 + prr) & 127;
            const float* src =
                x + ((size_t)(b * 32 + pig * 8) * HH + grow) * WW + pcp * 2;
            #pragma unroll
            for (int jj = 0; jj < 8; ++jj)
                pf[jj] = *(const float2*)(src + (size_t)jj * HH * WW);
        }
        f32x4 acc[2][2];
        #pragma unroll
        for (int oh = 0; oh < 2; ++oh)
            #pragma unroll
            for (int q = 0; q < 2; ++q) acc[oh][q] = (f32x4){0.f, 0.f, 0.f, 0.f};
        const int hr = 2 * c + row;
        #pragma unroll
        for (int lc = 0; lc < 3; ++lc) {
            #pragma unroll
            for (int k = 0; k < 3; ++k) {
                int s = hr + k; s = (s >= 6) ? s - 6 : s;
                const bf16x8 a0 = af[k * 3 + lc][0];
                const bf16x8 a1 = af[k * 3 + lc][1];
                #pragma unroll
                for (int q = 0; q < 2; ++q) {
                    int t = (bb[lc] + (nq * 2 + q) * 64) & 511;
                    bf16x8 bfv = lds_x[s * 512 + t];
                    acc[0][q] = __builtin_amdgcn_mfma_f32_16x16x32_bf16(
                        a0, bfv, acc[0][q], 0, 0, 0);
                    acc[1][q] = __builtin_amdgcn_mfma_f32_16x16x32_bf16(
                        a1, bfv, acc[1][q], 0, 0, 0);
                }
            }
        }
        const size_t ob = obase0 + (size_t)(h0 + hr) * WW;
        #pragma unroll
        for (int oh = 0; oh < 2; ++oh)
            #pragma unroll
            for (int q = 0; q < 2; ++q)
                #pragma unroll
                for (int r = 0; r < 4; ++r)
                    __builtin_nontemporal_store(
                        acc[oh][q][r] + blr[oh][r],
                        &out[ob + (size_t)(oh * 16 + r) * (HH * WW) +
                             (nq * 2 + q) * 16]);
        if (c < 3) {
            u32 p0[4], p1[4];
            #pragma unroll
            for (int q = 0; q < 4; ++q) {
                p0[q] = cvt_pk_bf16(pf[2 * q].x, pf[2 * q + 1].x);
                p1[q] = cvt_pk_bf16(pf[2 * q].y, pf[2 * q + 1].y);
            }
            int wslot = (prr >= 6) ? prr - 6 : prr;
            int c0 = pcp * 2;
            int didx = wslot * 512 + (c0 >> 4) * 64 + pig * 16 + (c0 & 15);
            *(uint4*)&lds_x[didx]     = make_uint4(p0[0], p0[1], p0[2], p0[3]);
            *(uint4*)&lds_x[didx + 1] = make_uint4(p1[0], p1[1], p1[2], p1[3]);
            lds_barrier();
        }
    }
}

extern "C" void kernel_launch(void* const* d_in, const int* in_sizes, int n_in,
                              void* d_out, int out_size, void* d_ws, size_t ws_size,
                              hipStream_t stream) {
    const float* x      = (const float*)d_in[0];
    const float* codes  = (const float*)d_in[1];
    const float* weight = (const float*)d_in[2];
    const float* A      = (const float*)d_in[3];
    const float* Bm     = (const float*)d_in[4];
    const float* bias   = (const float*)d_in[5];
    const float* bctx   = (const float*)d_in[6];
    float* out = (float*)d_out;

    const size_t need = (size_t)16 * 128 * 512 * 16;   // 16.78 MB
    if (ws_size >= need) {
        u32* xb16 = (u32*)d_ws;
        hipLaunchKernelGGL(geps_pack_kernel, dim3(2048), dim3(256), 0, stream,
                           x, xb16);
        hipLaunchKernelGGL(geps_conv_kernel, dim3(256), dim3(512), 0, stream,
                           xb16, codes, weight, A, Bm, bias, bctx, out);
    } else {
        hipLaunchKernelGGL(geps_mono_kernel, dim3(256), dim3(512), 0, stream,
                           x, codes, weight, A, Bm, bias, bctx, out);
    }
}

// Round 14
// 21.399 us; speedup vs baseline: 1.4233x; 1.4233x over previous
//
#include <hip/hip_runtime.h>

typedef short bf16x8 __attribute__((ext_vector_type(8)));
typedef float f32x4  __attribute__((ext_vector_type(4)));
typedef unsigned int u32;

#define HH 128
#define WW 128

__device__ __forceinline__ u32 cvt_pk_bf16(float lo, float hi) {
    u32 r;
    asm volatile("v_cvt_pk_bf16_f32 %0, %1, %2" : "=v"(r) : "v"(lo), "v"(hi));
    return r;   // low16 = bf16(lo), high16 = bf16(hi)
}

// LDS-only barrier (does not drain global loads/stores).
__device__ __forceinline__ void lds_barrier() {
    asm volatile("s_waitcnt lgkmcnt(0)" ::: "memory");
    __builtin_amdgcn_s_barrier();
    __builtin_amdgcn_sched_barrier(0);
}

// Implicit-GEMM conv via 9 shifted 32x32 channel GEMMs on mfma_f32_16x16x32_bf16.
// Block: 1024 thr (16 waves) owns 8 contiguous output rows of one batch.
// All 20 x-loads per thread issued at cycle 0 (each load instr = one 512B
// contiguous row segment); ctx+weight synthesis overlaps their latency.
// Compute wave = (row 0..7, nh 0..1), flat 10-slot LDS x buffer.
// COALESCED EPILOGUE: acc -> 64KB f32 LDS bounce (reusing lds_x; per-channel
// col-rotation kills bank conflicts) -> each wave streams 1KB-contiguous
// nontemporal dwordx4 stores (4KB sequential per output channel).
// Grid: 256 blocks (16 b x 16 groups), XCD-bijective swizzle, 1 block/CU.
__global__ __launch_bounds__(1024, 1) void geps_mfma_kernel(
    const float* __restrict__ x, const float* __restrict__ codes,
    const float* __restrict__ weight, const float* __restrict__ A,
    const float* __restrict__ Bm, const float* __restrict__ bias,
    const float* __restrict__ bctx, float* __restrict__ out)
{
    __shared__ bf16x8 lds_x[5120];    // [10 slots][512 entries] = 80 KB (+ bounce)
    __shared__ bf16x8 lds_w[1152];    // [9 kl][2 oh][4 kb][16 o] x 8i bf16
    __shared__ float  lds_ctx[576];
    __shared__ float  lds_b[32];

    const int tid  = threadIdx.x;
    const int l    = tid & 63;
    const int wvid = tid >> 6;         // 0..15
    const int row  = wvid >> 1;        // 0..7
    const int nh   = wvid & 1;         // col-tile half

    // XCD-aware bijective swizzle: 256 blocks = 8 XCDs x 32 contiguous.
    const int orig = blockIdx.x;
    const int vb   = (orig & 7) * 32 + (orig >> 3);
    const int b    = vb >> 4;          // batch 0..15
    const int grp  = vb & 15;          // 8-row group 0..15
    const int h0   = grp * 8;

    // ---- Issue ALL x loads now (rows h0-1..h0+8); 5 items x 4 float2.
    //      item: cp = lane bits -> each load instr = 512B contiguous. ----
    float2 f[5][4];
    #pragma unroll
    for (int it = 0; it < 5; ++it) {
        int idx = it * 1024 + tid;     // < 5120
        int cp = idx & 63, jh = (idx >> 6) & 1, ig = (idx >> 7) & 3, rr = idx >> 9;
        int grow = (h0 - 1 + rr) & 127;
        const float* src =
            x + ((size_t)(b * 32 + ig * 8 + jh * 4) * HH + grow) * WW + cp * 2;
        #pragma unroll
        for (int jj = 0; jj < 4; ++jj)
            f[it][jj] = *(const float2*)(src + (size_t)jj * HH * WW);
    }

    // ---- ctx + bias (overlaps load latency) ----
    const float c00 = codes[b * 4 + 0];
    const float c01 = codes[b * 4 + 1];
    const float c10 = codes[b * 4 + 2];
    const float c11 = codes[b * 4 + 3];
    if (tid < 576) {
        int j = tid;
        int i = j / 18, rem = j % 18, r = rem / 9, kl = rem % 9;
        float a0 = A[(i * 2 + 0) * 9 + kl];
        float a1 = A[(i * 2 + 1) * 9 + kl];
        lds_ctx[j] = (r == 0) ? (a0 * c00 + a1 * c10) : (a0 * c01 + a1 * c11);
    }
    if (tid < 32) lds_b[tid] = bias[tid] + c00 * bctx[tid] + c11 * bctx[32 + tid];
    lds_barrier();   // ctx visible

    // ---- Weight synthesis -> bf16 LDS (still overlapping load latency) ----
    for (int j = tid; j < 1152; j += 1024) {
        int kl = j >> 7, rem = j & 127, o = rem >> 2, kb = rem & 3;
        float m0 = Bm[(o * 2 + 0) * 9 + kl];
        float m1 = Bm[(o * 2 + 1) * 9 + kl];
        float wf[8];
        #pragma unroll
        for (int jj = 0; jj < 8; ++jj) {
            int i = kb * 8 + jj;
            wf[jj] = weight[(o * 32 + i) * 9 + kl]
                   + lds_ctx[i * 18 + kl] * m0
                   + lds_ctx[i * 18 + 9 + kl] * m1;
        }
        u32 pk[4];
        #pragma unroll
        for (int q = 0; q < 4; ++q) pk[q] = cvt_pk_bf16(wf[2 * q], wf[2 * q + 1]);
        *(uint4*)&lds_w[kl * 128 + (o >> 4) * 64 + kb * 16 + (o & 15)] =
            make_uint4(pk[0], pk[1], pk[2], pk[3]);
    }

    // ---- Convert + write staged x to LDS (waits on loads per-item) ----
    #pragma unroll
    for (int it = 0; it < 5; ++it) {
        int idx = it * 1024 + tid;
        int cp = idx & 63, jh = (idx >> 6) & 1, ig = (idx >> 7) & 3, rr = idx >> 9;
        int c0 = cp * 2;
        u32 a0 = cvt_pk_bf16(f[it][0].x, f[it][1].x);
        u32 a1 = cvt_pk_bf16(f[it][2].x, f[it][3].x);
        u32 b0 = cvt_pk_bf16(f[it][0].y, f[it][1].y);
        u32 b1 = cvt_pk_bf16(f[it][2].y, f[it][3].y);
        int didx = (c0 >> 4) * 64 + ig * 16 + (c0 & 15);
        *(uint2*)((char*)lds_x + rr * 8192 + didx * 16 + jh * 8) =
            make_uint2(a0, a1);
        *(uint2*)((char*)lds_x + rr * 8192 + (didx + 1) * 16 + jh * 8) =
            make_uint2(b0, b1);
    }
    lds_barrier();   // staging + weights complete

    // ---- A fragments: all 9 taps x both oh halves (72 VGPRs) ----
    const int awb = (l >> 4) * 16 + (l & 15);
    bf16x8 af[9][2];
    #pragma unroll
    for (int kl = 0; kl < 9; ++kl)
        #pragma unroll
        for (int oh = 0; oh < 2; ++oh)
            af[kl][oh] = lds_w[kl * 128 + oh * 64 + awb];

    // ---- B-address bases per tap-column shift dl in {-1,0,1} ----
    const int p = l & 15, igf = l >> 4;
    int bb[3];
    #pragma unroll
    for (int dl = -1; dl <= 1; ++dl) {
        int pq = p + dl;                       // -1..16
        bb[dl + 1] = (pq & 15) + ((pq >> 4) << 6) + igf * 16;  // 16B-elem units
    }

    float blr[2][4];
    #pragma unroll
    for (int oh = 0; oh < 2; ++oh)
        #pragma unroll
        for (int r = 0; r < 4; ++r)
            blr[oh][r] = lds_b[oh * 16 + (l >> 4) * 4 + r];

    // ---- Main loop: wave = (row, nh); slots row..row+2 (flat) ----
    f32x4 acc[2][4];
    #pragma unroll
    for (int oh = 0; oh < 2; ++oh)
        #pragma unroll
        for (int q = 0; q < 4; ++q) acc[oh][q] = (f32x4){0.f, 0.f, 0.f, 0.f};

    #pragma unroll
    for (int lc = 0; lc < 3; ++lc) {
        #pragma unroll
        for (int k = 0; k < 3; ++k) {
            const bf16x8 a0 = af[k * 3 + lc][0];
            const bf16x8 a1 = af[k * 3 + lc][1];
            #pragma unroll
            for (int q = 0; q < 4; ++q) {
                int t = (bb[lc] + (nh * 4 + q) * 64) & 511;  // col wrap
                bf16x8 bfv = lds_x[(row + k) * 512 + t];
                acc[0][q] = __builtin_amdgcn_mfma_f32_16x16x32_bf16(
                    a0, bfv, acc[0][q], 0, 0, 0);
                acc[1][q] = __builtin_amdgcn_mfma_f32_16x16x32_bf16(
                    a1, bfv, acc[1][q], 0, 0, 0);
            }
        }
    }

    // ---- Coalesced epilogue: 2 rounds of 16 channels via LDS bounce ----
    // Writer: D-frag element (o16 = (l>>4)*4+r, col) -> bounce[o16][row][col]
    //   with col rotated by 4*o16 (bank-conflict-free: bank = (l + 4r) & 31).
    // Reader: wave w streams channel (oh*16 + w): 4 x dwordx4, each 1KB
    //   contiguous (2 full output rows), nontemporal.
    float* bounce = (float*)lds_x;
    #pragma unroll
    for (int oh = 0; oh < 2; ++oh) {
        lds_barrier();   // lds_x free (MFMA reads / previous round's reads done)
        #pragma unroll
        for (int q = 0; q < 4; ++q)
            #pragma unroll
            for (int r = 0; r < 4; ++r) {
                int o16  = (l >> 4) * 4 + r;
                int col  = (nh * 4 + q) * 16 + (l & 15);
                int col2 = (col + o16 * 4) & 127;
                bounce[(o16 * 8 + row) * 128 + col2] = acc[oh][q][r] + blr[oh][r];
            }
        lds_barrier();
        const int ch = oh * 16 + wvid;   // wave w owns channel oh*16+w
        #pragma unroll
        for (int k = 0; k < 4; ++k) {
            int hrow = 2 * k + (l >> 5);
            int lcol = (l & 31) * 4;
            int pcol = (lcol + wvid * 4) & 127;
            f32x4 v = *(const f32x4*)&bounce[(wvid * 8 + hrow) * 128 + pcol];
            __builtin_nontemporal_store(
                v, (f32x4*)&out[((size_t)(b * 32 + ch) * HH + (h0 + hrow)) * WW +
                                lcol]);
        }
    }
}

extern "C" void kernel_launch(void* const* d_in, const int* in_sizes, int n_in,
                              void* d_out, int out_size, void* d_ws, size_t ws_size,
                              hipStream_t stream) {
    const float* x      = (const float*)d_in[0];
    const float* codes  = (const float*)d_in[1];
    const float* weight = (const float*)d_in[2];
    const float* A      = (const float*)d_in[3];
    const float* Bm     = (const float*)d_in[4];
    const float* bias   = (const float*)d_in[5];
    const float* bctx   = (const float*)d_in[6];
    float* out = (float*)d_out;

    hipLaunchKernelGGL(geps_mfma_kernel, dim3(256), dim3(1024), 0, stream,
                       x, codes, weight, A, Bm, bias, bctx, out);
}

// Round 15
// 21.262 us; speedup vs baseline: 1.4325x; 1.0065x over previous
//
#include <hip/hip_runtime.h>

typedef short bf16x8 __attribute__((ext_vector_type(8)));
typedef float f32x4  __attribute__((ext_vector_type(4)));
typedef unsigned int u32;

#define HH 128
#define WW 128

__device__ __forceinline__ u32 cvt_pk_bf16(float lo, float hi) {
    u32 r;
    asm volatile("v_cvt_pk_bf16_f32 %0, %1, %2" : "=v"(r) : "v"(lo), "v"(hi));
    return r;   // low16 = bf16(lo), high16 = bf16(hi)
}

// LDS-only barrier (does not drain global loads/stores).
__device__ __forceinline__ void lds_barrier() {
    asm volatile("s_waitcnt lgkmcnt(0)" ::: "memory");
    __builtin_amdgcn_s_barrier();
    __builtin_amdgcn_sched_barrier(0);
}

// Implicit-GEMM conv via 9 shifted 32x32 channel GEMMs on mfma_f32_16x16x32_bf16.
// Block: 1024 thr (16 waves) owns 8 contiguous output rows of one batch.
// Prologue (= R14): all 20 x-loads issued at cycle 0 (512B-contiguous per
// instr), ctx+weight synthesis overlaps load latency, one staging pass into
// a flat 10-slot LDS buffer.
// NEW: rows processed as TWO 4-row chunks.  Chunk0: compute -> coalesced
// bounce epilogue (bounce reuses slots 0..3, freed by chunk0's compute).
// Chunk1 compute starts with NO barrier (slots 4..9 disjoint from bounce),
// so chunk0's nontemporal store burst drains underneath it.
// Wave = (row4 0..3, nq 0..3): 1 row, 2 col-tiles, all 32 out-ch.
// Grid: 256 blocks (16 b x 16 groups), XCD-bijective swizzle, 1 block/CU.
__global__ __launch_bounds__(1024, 1) void geps_mfma_kernel(
    const float* __restrict__ x, const float* __restrict__ codes,
    const float* __restrict__ weight, const float* __restrict__ A,
    const float* __restrict__ Bm, const float* __restrict__ bias,
    const float* __restrict__ bctx, float* __restrict__ out)
{
    __shared__ bf16x8 lds_x[5120];    // [10 slots][512 entries] = 80 KB (+ bounce)
    __shared__ bf16x8 lds_w[1152];    // [9 kl][2 oh][4 kb][16 o] x 8i bf16
    __shared__ float  lds_ctx[576];
    __shared__ float  lds_b[32];

    const int tid  = threadIdx.x;
    const int l    = tid & 63;
    const int wvid = tid >> 6;         // 0..15
    const int row4 = wvid >> 2;        // 0..3 (row within 4-row chunk)
    const int nq   = wvid & 3;         // 0..3 (col-tiles nq*2, nq*2+1)

    // XCD-aware bijective swizzle: 256 blocks = 8 XCDs x 32 contiguous.
    const int orig = blockIdx.x;
    const int vb   = (orig & 7) * 32 + (orig >> 3);
    const int b    = vb >> 4;          // batch 0..15
    const int grp  = vb & 15;          // 8-row group 0..15
    const int h0   = grp * 8;

    // ---- Issue ALL x loads now (rows h0-1..h0+8); 5 items x 4 float2 ----
    float2 f[5][4];
    #pragma unroll
    for (int it = 0; it < 5; ++it) {
        int idx = it * 1024 + tid;     // < 5120
        int cp = idx & 63, jh = (idx >> 6) & 1, ig = (idx >> 7) & 3, rr = idx >> 9;
        int grow = (h0 - 1 + rr) & 127;
        const float* src =
            x + ((size_t)(b * 32 + ig * 8 + jh * 4) * HH + grow) * WW + cp * 2;
        #pragma unroll
        for (int jj = 0; jj < 4; ++jj)
            f[it][jj] = *(const float2*)(src + (size_t)jj * HH * WW);
    }

    // ---- ctx + bias (overlaps load latency) ----
    const float c00 = codes[b * 4 + 0];
    const float c01 = codes[b * 4 + 1];
    const float c10 = codes[b * 4 + 2];
    const float c11 = codes[b * 4 + 3];
    if (tid < 576) {
        int j = tid;
        int i = j / 18, rem = j % 18, r = rem / 9, kl = rem % 9;
        float a0 = A[(i * 2 + 0) * 9 + kl];
        float a1 = A[(i * 2 + 1) * 9 + kl];
        lds_ctx[j] = (r == 0) ? (a0 * c00 + a1 * c10) : (a0 * c01 + a1 * c11);
    }
    if (tid < 32) lds_b[tid] = bias[tid] + c00 * bctx[tid] + c11 * bctx[32 + tid];
    lds_barrier();   // ctx visible

    // ---- Weight synthesis -> bf16 LDS (still overlapping load latency) ----
    for (int j = tid; j < 1152; j += 1024) {
        int kl = j >> 7, rem = j & 127, o = rem >> 2, kb = rem & 3;
        float m0 = Bm[(o * 2 + 0) * 9 + kl];
        float m1 = Bm[(o * 2 + 1) * 9 + kl];
        float wf[8];
        #pragma unroll
        for (int jj = 0; jj < 8; ++jj) {
            int i = kb * 8 + jj;
            wf[jj] = weight[(o * 32 + i) * 9 + kl]
                   + lds_ctx[i * 18 + kl] * m0
                   + lds_ctx[i * 18 + 9 + kl] * m1;
        }
        u32 pk[4];
        #pragma unroll
        for (int q = 0; q < 4; ++q) pk[q] = cvt_pk_bf16(wf[2 * q], wf[2 * q + 1]);
        *(uint4*)&lds_w[kl * 128 + (o >> 4) * 64 + kb * 16 + (o & 15)] =
            make_uint4(pk[0], pk[1], pk[2], pk[3]);
    }

    // ---- Convert + write staged x to LDS ----
    #pragma unroll
    for (int it = 0; it < 5; ++it) {
        int idx = it * 1024 + tid;
        int cp = idx & 63, jh = (idx >> 6) & 1, ig = (idx >> 7) & 3, rr = idx >> 9;
        int c0 = cp * 2;
        u32 a0 = cvt_pk_bf16(f[it][0].x, f[it][1].x);
        u32 a1 = cvt_pk_bf16(f[it][2].x, f[it][3].x);
        u32 b0 = cvt_pk_bf16(f[it][0].y, f[it][1].y);
        u32 b1 = cvt_pk_bf16(f[it][2].y, f[it][3].y);
        int didx = (c0 >> 4) * 64 + ig * 16 + (c0 & 15);
        *(uint2*)((char*)lds_x + rr * 8192 + didx * 16 + jh * 8) =
            make_uint2(a0, a1);
        *(uint2*)((char*)lds_x + rr * 8192 + (didx + 1) * 16 + jh * 8) =
            make_uint2(b0, b1);
    }
    lds_barrier();   // staging + weights complete

    // ---- A fragments: all 9 taps x both oh halves (72 VGPRs) ----
    const int awb = (l >> 4) * 16 + (l & 15);
    bf16x8 af[9][2];
    #pragma unroll
    for (int kl = 0; kl < 9; ++kl)
        #pragma unroll
        for (int oh = 0; oh < 2; ++oh)
            af[kl][oh] = lds_w[kl * 128 + oh * 64 + awb];

    // ---- B-address bases per tap-column shift dl in {-1,0,1} ----
    const int p = l & 15, igf = l >> 4;
    int bb[3];
    #pragma unroll
    for (int dl = -1; dl <= 1; ++dl) {
        int pq = p + dl;                       // -1..16
        bb[dl + 1] = (pq & 15) + ((pq >> 4) << 6) + igf * 16;  // 16B-elem units
    }

    float blr[2][4];
    #pragma unroll
    for (int oh = 0; oh < 2; ++oh)
        #pragma unroll
        for (int r = 0; r < 4; ++r)
            blr[oh][r] = lds_b[oh * 16 + (l >> 4) * 4 + r];

    // ---- Two 4-row chunks: compute -> bounce epilogue; chunk1 compute
    //      overlaps chunk0's store drain (no barrier between). ----
    #pragma unroll
    for (int c = 0; c < 2; ++c) {
        // Compute chunk c: output rows h0+4c+row4, slots 4c+row4+k.
        f32x4 acc[2][2];
        #pragma unroll
        for (int oh = 0; oh < 2; ++oh)
            #pragma unroll
            for (int q = 0; q < 2; ++q) acc[oh][q] = (f32x4){0.f, 0.f, 0.f, 0.f};

        #pragma unroll
        for (int lc = 0; lc < 3; ++lc) {
            #pragma unroll
            for (int k = 0; k < 3; ++k) {
                const bf16x8 a0 = af[k * 3 + lc][0];
                const bf16x8 a1 = af[k * 3 + lc][1];
                const int s = 4 * c + row4 + k;
                #pragma unroll
                for (int q = 0; q < 2; ++q) {
                    int t = (bb[lc] + (nq * 2 + q) * 64) & 511;  // col wrap
                    bf16x8 bfv = lds_x[s * 512 + t];
                    acc[0][q] = __builtin_amdgcn_mfma_f32_16x16x32_bf16(
                        a0, bfv, acc[0][q], 0, 0, 0);
                    acc[1][q] = __builtin_amdgcn_mfma_f32_16x16x32_bf16(
                        a1, bfv, acc[1][q], 0, 0, 0);
                }
            }
        }

        // Coalesced epilogue: bounce region = slots 4c..4c+3 (32 KB), freed
        // by chunk c's own compute (chunk1 reads slots 4..9 only).
        float* bounce = (float*)((char*)lds_x + 4 * c * 8192);
        #pragma unroll
        for (int oh = 0; oh < 2; ++oh) {
            lds_barrier();   // compute reads (c) / previous round reads done
            #pragma unroll
            for (int q = 0; q < 2; ++q)
                #pragma unroll
                for (int r = 0; r < 4; ++r) {
                    int o16  = (l >> 4) * 4 + r;
                    int col  = (nq * 2 + q) * 16 + (l & 15);
                    int col2 = (col + o16 * 4) & 127;
                    bounce[(o16 * 4 + row4) * 128 + col2] =
                        acc[oh][q][r] + blr[oh][r];
                }
            lds_barrier();
            const int ch = oh * 16 + wvid;   // wave w streams channel oh*16+w
            #pragma unroll
            for (int k2 = 0; k2 < 2; ++k2) {
                int hrow = 2 * k2 + (l >> 5);
                int lcol = (l & 31) * 4;
                int pcol = (lcol + wvid * 4) & 127;
                f32x4 v = *(const f32x4*)&bounce[(wvid * 4 + hrow) * 128 + pcol];
                __builtin_nontemporal_store(
                    v, (f32x4*)&out[((size_t)(b * 32 + ch) * HH +
                                     (h0 + 4 * c + hrow)) * WW + lcol]);
            }
        }
        if (c == 0) lds_barrier();   // oh1 bounce reads done before... (next
        // chunk's compute touches slots 4..9 only, but keep reads/writes of
        // the shared LDS pipe ordered cheaply)
    }
}

extern "C" void kernel_launch(void* const* d_in, const int* in_sizes, int n_in,
                              void* d_out, int out_size, void* d_ws, size_t ws_size,
                              hipStream_t stream) {
    const float* x      = (const float*)d_in[0];
    const float* codes  = (const float*)d_in[1];
    const float* weight = (const float*)d_in[2];
    const float* A      = (const float*)d_in[3];
    const float* Bm     = (const float*)d_in[4];
    const float* bias   = (const float*)d_in[5];
    const float* bctx   = (const float*)d_in[6];
    float* out = (float*)d_out;

    hipLaunchKernelGGL(geps_mfma_kernel, dim3(256), dim3(1024), 0, stream,
                       x, codes, weight, A, Bm, bias, bctx, out);
}